// Round 1
// baseline (619.254 us; speedup 1.0000x reference)
//
#include <hip/hip_runtime.h>
#include <hip/hip_bf16.h>

typedef unsigned short u16;
typedef unsigned int   u32;
typedef float  f32x4  __attribute__((ext_vector_type(4)));
typedef __bf16 bf16x8 __attribute__((ext_vector_type(8)));
typedef u16    u16x8  __attribute__((ext_vector_type(8)));
typedef u16    u16x4  __attribute__((ext_vector_type(4)));

__device__ __forceinline__ u16 f2bf(float f) {
  u32 x = __builtin_bit_cast(u32, f);
  x += 0x7fffu + ((x >> 16) & 1u);          // RNE
  return (u16)(x >> 16);
}
__device__ __forceinline__ float bf2f(u16 u) {
  return __builtin_bit_cast(float, (u32)u << 16);
}
__device__ __forceinline__ void gload_lds16(const u16* g, u16* l) {
  __builtin_amdgcn_global_load_lds(
      (const __attribute__((address_space(1))) void*)g,
      (__attribute__((address_space(3))) void*)l, 16, 0, 0);
}

// ---------------- convert x -> bf16 (each thread: 8 elems) ----------------
__global__ void k_conv_x(const float* __restrict__ x, u16* __restrict__ xb) {
  int g = blockIdx.x * 256 + threadIdx.x;          // 4,194,304 threads exact
  const float4* src = (const float4*)(x + (size_t)g * 8);
  float4 f0 = src[0], f1 = src[1];
  u16x8 o;
  o[0]=f2bf(f0.x); o[1]=f2bf(f0.y); o[2]=f2bf(f0.z); o[3]=f2bf(f0.w);
  o[4]=f2bf(f1.x); o[5]=f2bf(f1.y); o[6]=f2bf(f1.z); o[7]=f2bf(f1.w);
  *(u16x8*)(xb + (size_t)g * 8) = o;
}

// ------------- convert weights -> bf16, build concat bias -----------------
__global__ void k_conv_w(const float* __restrict__ Wu, const float* __restrict__ Wv,
                         const float* __restrict__ Wo, const float* __restrict__ bu,
                         const float* __restrict__ bv, u16* __restrict__ wuvb,
                         u16* __restrict__ wob, float* __restrict__ biasuv) {
  int g = blockIdx.x * 256 + threadIdx.x;          // 393,216 threads exact
  int e = g * 4;
  const float* src; u16* dst;
  if (e < 524288)        { src = Wu + e;             dst = wuvb + e; }
  else if (e < 1048576)  { src = Wv + (e - 524288);  dst = wuvb + e; }
  else                   { src = Wo + (e - 1048576); dst = wob + (e - 1048576); }
  float4 f = *(const float4*)src;
  u16x4 o; o[0]=f2bf(f.x); o[1]=f2bf(f.y); o[2]=f2bf(f.z); o[3]=f2bf(f.w);
  *(u16x4*)dst = o;
  if (g < 2048) biasuv[g] = (g < 1024) ? bu[g] : bv[g - 1024];
}

// ------------- T matrices: T[h] = (Wm U)(Wm V)^T, 64x64 per head ----------
// grid 128: which = bid>>6 (0:T1 scale1, 1:T2 scale2), h=(bid&63)>>3, seg=bid&7
__global__ void k_toep(const float* __restrict__ U1, const float* __restrict__ V1,
                       const float* __restrict__ U2, const float* __restrict__ V2,
                       u16* __restrict__ T1b, u16* __restrict__ T2b) {
  __shared__ float Us[512], Vs[512];
  int bid = blockIdx.x, t = threadIdx.x;
  int which = bid >> 6, rest = bid & 63, h = rest >> 3, seg = rest & 7;
  const float* U = which ? U2 : U1;
  const float* V = which ? V2 : V1;
  u16* T = which ? T2b : T1b;
  float scale = which ? 2.0f : 1.0f;
  for (int i = t; i < 512; i += 256) { Us[i] = U[h*512 + i]; Vs[i] = V[h*512 + i]; }
  __syncthreads();
  for (int q = 0; q < 2; ++q) {
    int e = seg * 512 + q * 256 + t;               // 0..4095 per head
    int i = e >> 6, j = e & 63;
    float pi = 1.0f / (float)(i + 1); float tvi = pi * 15.0f;
    int ii = min((int)floorf(tvi), 14); float fi = tvi - (float)ii;
    float pj = 1.0f / (float)(j + 1); float tvj = pj * 15.0f;
    int jj = min((int)floorf(tvj), 14); float fj = tvj - (float)jj;
    float s = 0.0f;
    #pragma unroll
    for (int r = 0; r < 32; ++r) {
      float a = (1.0f - fi) * Us[ii*32 + r] + fi * Us[(ii+1)*32 + r];
      float b = (1.0f - fj) * Vs[jj*32 + r] + fj * Vs[(jj+1)*32 + r];
      s += a * b;
    }
    T[h*4096 + i*64 + j] = f2bf(s * scale);
  }
}

// ---------------- 128x128 bf16 B^T GEMM (m97 structure) -------------------
// C[m,n] = sum_k A[m,k]*B[n,k] (+bias[n]); EPI 0: silu->bf16, EPI 1: f32
template<int EPI>
__global__ __launch_bounds__(256) void k_gemm(const u16* __restrict__ A,
    const u16* __restrict__ B, const float* __restrict__ bias,
    void* __restrict__ C, int K, int nbn, int ldc) {
  __shared__ alignas(16) u16 As[128 * 64];
  __shared__ alignas(16) u16 Bs[128 * 64];
  int bid = blockIdx.x;
  int bm = bid / nbn, bn = bid % nbn;
  int t = threadIdx.x, l = t & 63, w = t >> 6;
  const u16* Ab = A + (size_t)bm * 128 * K;
  const u16* Bb = B + (size_t)bn * 128 * K;
  f32x4 acc[4][4];
  #pragma unroll
  for (int i = 0; i < 4; ++i)
    #pragma unroll
    for (int j = 0; j < 4; ++j) acc[i][j] = (f32x4){0.f, 0.f, 0.f, 0.f};
  int wm = (w >> 1) * 64, wn = (w & 1) * 64;
  for (int kt = 0; kt < K; kt += 64) {
    #pragma unroll
    for (int q = 0; q < 4; ++q) {
      int c = q * 256 + t;
      int row = c >> 3, col = (c & 7) * 8;
      gload_lds16(Ab + (size_t)row * K + kt + col, &As[c * 8]);
    }
    #pragma unroll
    for (int q = 0; q < 4; ++q) {
      int c = q * 256 + t;
      int row = c >> 3, col = (c & 7) * 8;
      gload_lds16(Bb + (size_t)row * K + kt + col, &Bs[c * 8]);
    }
    __syncthreads();
    #pragma unroll
    for (int ks = 0; ks < 2; ++ks) {
      bf16x8 af[4], bfr[4];
      #pragma unroll
      for (int mf = 0; mf < 4; ++mf)
        af[mf] = *(const bf16x8*)&As[(wm + mf*16 + (l & 15)) * 64 + ks*32 + (l >> 4)*8];
      #pragma unroll
      for (int nf = 0; nf < 4; ++nf)
        bfr[nf] = *(const bf16x8*)&Bs[(wn + nf*16 + (l & 15)) * 64 + ks*32 + (l >> 4)*8];
      #pragma unroll
      for (int mf = 0; mf < 4; ++mf)
        #pragma unroll
        for (int nf = 0; nf < 4; ++nf)
          acc[mf][nf] = __builtin_amdgcn_mfma_f32_16x16x32_bf16(af[mf], bfr[nf], acc[mf][nf], 0, 0, 0);
    }
    __syncthreads();
  }
  #pragma unroll
  for (int mf = 0; mf < 4; ++mf) {
    int gm0 = bm * 128 + wm + mf * 16 + (l >> 4) * 4;
    #pragma unroll
    for (int nf = 0; nf < 4; ++nf) {
      int gn = bn * 128 + wn + nf * 16 + (l & 15);
      float bi = bias[gn];
      #pragma unroll
      for (int r = 0; r < 4; ++r) {
        float z = acc[mf][nf][r] + bi;
        size_t off = (size_t)(gm0 + r) * ldc + gn;
        if (EPI == 0) {
          z = z / (1.0f + __expf(-z));           // silu
          ((u16*)C)[off] = f2bf(z);
        } else {
          ((float*)C)[off] = z;
        }
      }
    }
  }
}

// ------------- mixing pass: per (b,outer,h): Out = T @ In (64x64 @ 64x128) -
// PASS 0: In = v (uv col 1024+), along W (outer=i), write y.
// PASS 1: In = y, along H (outer=j), T2 already x2; gate by u; in-place on y.
template<int PASS>
__global__ __launch_bounds__(256) void k_mix(const u16* __restrict__ uv,
                                             u16* __restrict__ y,
                                             const u16* __restrict__ Tmat) {
  __shared__ alignas(16) u16 Ts[64 * 72];     // T padded rows (72 elems)
  __shared__ alignas(16) u32 VT[128 * 36];    // transposed input, swizzled
  int bid = blockIdx.x, t = threadIdx.x;
  int h = bid & 7, outer = (bid >> 3) & 63, b = bid >> 9;
  int l = t & 63, w = t >> 6;

  { // stage T[h] (64x64 bf16) into padded LDS
    const u16* Tg = Tmat + h * 4096;
    int rr = t >> 2, cc = (t & 3) * 16;
    const uint4* src = (const uint4*)(Tg + rr * 64 + cc);
    uint4 v0 = src[0], v1 = src[1];
    *(uint4*)&Ts[rr * 72 + cc] = v0;
    *(uint4*)&Ts[rr * 72 + cc + 8] = v1;
  }

  size_t inbase; size_t instride;
  if (PASS == 0) { inbase = ((size_t)(b*64 + outer) * 64) * 2048 + 1024 + h*128; instride = 2048; }
  else           { inbase = ((size_t)b * 4096 + outer) * 1024 + h*128;            instride = 65536; }
  const u16* inp = (PASS == 0) ? uv : (const u16*)y;

  #pragma unroll
  for (int a2 = 0; a2 < 2; ++a2) {
    int jp = (t >> 4) + a2 * 16;                 // row-pair 0..31 (rows 2jp,2jp+1)
    int dc = t & 15;                             // d-chunk of 8
    const u16* r0 = inp + inbase + (size_t)(2*jp) * instride + dc * 8;
    const u16* r1 = r0 + instride;
    uint4 av = *(const uint4*)r0;
    uint4 bv = *(const uint4*)r1;
    u32 a4[4] = {av.x, av.y, av.z, av.w};
    u32 b4[4] = {bv.x, bv.y, bv.z, bv.w};
    #pragma unroll
    for (int ww = 0; ww < 4; ++ww) {
      u32 lo = (a4[ww] & 0xffffu) | (b4[ww] << 16);        // d even
      u32 hi = (a4[ww] >> 16) | (b4[ww] & 0xffff0000u);    // d odd
      int d0 = dc * 8 + 2 * ww, d1 = d0 + 1;
      VT[d0 * 36 + (jp ^ ((((u32)d0 >> 3) & 7) << 2))] = lo;
      VT[d1 * 36 + (jp ^ ((((u32)d1 >> 3) & 7) << 2))] = hi;
    }
  }
  __syncthreads();

  f32x4 acc[8];
  #pragma unroll
  for (int nf = 0; nf < 8; ++nf) acc[nf] = (f32x4){0.f, 0.f, 0.f, 0.f};
  #pragma unroll
  for (int ks = 0; ks < 2; ++ks) {
    bf16x8 af = *(const bf16x8*)&Ts[(w*16 + (l & 15)) * 72 + ks*32 + (l >> 4)*8];
    #pragma unroll
    for (int nf = 0; nf < 8; ++nf) {
      int d  = nf * 16 + (l & 15);
      int kd = ks * 16 + (l >> 4) * 4;
      u32 dw = (u32)d * 36 + ((u32)kd ^ ((((u32)d >> 3) & 7) << 2));
      bf16x8 bfv = *(const bf16x8*)&VT[dw];
      acc[nf] = __builtin_amdgcn_mfma_f32_16x16x32_bf16(af, bfv, acc[nf], 0, 0, 0);
    }
  }

  size_t obase, ostride, ubase = 0;
  if (PASS == 0) { obase = ((size_t)(b*64 + outer) * 64) * 1024 + h*128; ostride = 1024; }
  else {
    obase = ((size_t)b * 4096 + outer) * 1024 + h*128; ostride = 65536;
    ubase = ((size_t)b * 4096 + outer) * 2048 + h*128;
  }
  #pragma unroll
  for (int nf = 0; nf < 8; ++nf) {
    int d = nf * 16 + (l & 15);
    #pragma unroll
    for (int r = 0; r < 4; ++r) {
      int m = w * 16 + (l >> 4) * 4 + r;
      float val = acc[nf][r];
      if (PASS == 1) val *= bf2f(uv[ubase + (size_t)m * 131072 + d]);
      y[obase + (size_t)m * ostride + d] = f2bf(val);
    }
  }
}

// ---------------------------------------------------------------------------
extern "C" void kernel_launch(void* const* d_in, const int* in_sizes, int n_in,
                              void* d_out, int out_size, void* d_ws, size_t ws_size,
                              hipStream_t stream) {
  const float* x  = (const float*)d_in[0];
  const float* Wu = (const float*)d_in[1];
  const float* bu = (const float*)d_in[2];
  const float* Wv = (const float*)d_in[3];
  const float* bv = (const float*)d_in[4];
  const float* Wo = (const float*)d_in[5];
  const float* bo = (const float*)d_in[6];
  const float* U1 = (const float*)d_in[7];
  const float* V1 = (const float*)d_in[8];
  const float* U2 = (const float*)d_in[9];
  const float* V2 = (const float*)d_in[10];
  float* out = (float*)d_out;

  char* p = (char*)d_ws;
  u16*  xb     = (u16*)(p + 0);              //  67,108,864 B
  u16*  wuvb   = (u16*)(p + 67108864);       //   2,097,152 B
  u16*  wob    = (u16*)(p + 69206016);       //   1,048,576 B
  u16*  T1b    = (u16*)(p + 70254592);       //      65,536 B
  u16*  T2b    = (u16*)(p + 70320128);       //      65,536 B
  float* biasuv= (float*)(p + 70385664);     //       8,192 B
  u16*  uv     = (u16*)(p + 70393856);       // 268,435,456 B  (u|v, ld 2048)
  u16*  y      = (u16*)(p + 338829312);      // 134,217,728 B  -> end 473,047,040
  if (ws_size < 473047040ULL) return;        // insufficient scratch: visible fail

  k_conv_x<<<16384, 256, 0, stream>>>(x, xb);
  k_conv_w<<<1536, 256, 0, stream>>>(Wu, Wv, Wo, bu, bv, wuvb, wob, biasuv);
  k_toep<<<128, 256, 0, stream>>>(U1, V1, U2, V2, T1b, T2b);
  // uv = [silu(x Wu^T + bu) | silu(x Wv^T + bv)]  (M=65536, N=2048, K=512)
  k_gemm<0><<<8192, 256, 0, stream>>>(xb, wuvb, biasuv, (void*)uv, 512, 16, 2048);
  // y = T1-mix along W of v
  k_mix<0><<<8192, 256, 0, stream>>>(uv, y, T1b);
  // y = u * (2*T2)-mix along H of y   (in-place, gated)
  k_mix<1><<<8192, 256, 0, stream>>>(uv, y, T2b);
  // out = y Wo^T + bo  (M=65536, N=512, K=1024)
  k_gemm<1><<<2048, 256, 0, stream>>>(y, wob, bo, (void*)out, 1024, 4, 512);
}

// Round 2
// 546.863 us; speedup vs baseline: 1.1324x; 1.1324x over previous
//
#include <hip/hip_runtime.h>
#include <hip/hip_bf16.h>

typedef unsigned short u16;
typedef unsigned int   u32;
typedef float  f32x4  __attribute__((ext_vector_type(4)));
typedef __bf16 bf16x8 __attribute__((ext_vector_type(8)));
typedef u16    u16x8  __attribute__((ext_vector_type(8)));
typedef u16    u16x4  __attribute__((ext_vector_type(4)));

__device__ __forceinline__ u16 f2bf(float f) {
  u32 x = __builtin_bit_cast(u32, f);
  x += 0x7fffu + ((x >> 16) & 1u);          // RNE
  return (u16)(x >> 16);
}
__device__ __forceinline__ float bf2f(u16 u) {
  return __builtin_bit_cast(float, (u32)u << 16);
}
__device__ __forceinline__ void gload_lds16(const u16* g, u16* l) {
  __builtin_amdgcn_global_load_lds(
      (const __attribute__((address_space(1))) void*)g,
      (__attribute__((address_space(3))) void*)l, 16, 0, 0);
}

// ---------------- convert x -> bf16 (each thread: 8 elems) ----------------
__global__ void k_conv_x(const float* __restrict__ x, u16* __restrict__ xb) {
  int g = blockIdx.x * 256 + threadIdx.x;          // 4,194,304 threads exact
  const float4* src = (const float4*)(x + (size_t)g * 8);
  float4 f0 = src[0], f1 = src[1];
  u16x8 o;
  o[0]=f2bf(f0.x); o[1]=f2bf(f0.y); o[2]=f2bf(f0.z); o[3]=f2bf(f0.w);
  o[4]=f2bf(f1.x); o[5]=f2bf(f1.y); o[6]=f2bf(f1.z); o[7]=f2bf(f1.w);
  *(u16x8*)(xb + (size_t)g * 8) = o;
}

// ------------- convert weights -> bf16, build concat bias -----------------
__global__ void k_conv_w(const float* __restrict__ Wu, const float* __restrict__ Wv,
                         const float* __restrict__ Wo, const float* __restrict__ bu,
                         const float* __restrict__ bv, u16* __restrict__ wuvb,
                         u16* __restrict__ wob, float* __restrict__ biasuv) {
  int g = blockIdx.x * 256 + threadIdx.x;          // 393,216 threads exact
  int e = g * 4;
  const float* src; u16* dst;
  if (e < 524288)        { src = Wu + e;             dst = wuvb + e; }
  else if (e < 1048576)  { src = Wv + (e - 524288);  dst = wuvb + e; }
  else                   { src = Wo + (e - 1048576); dst = wob + (e - 1048576); }
  float4 f = *(const float4*)src;
  u16x4 o; o[0]=f2bf(f.x); o[1]=f2bf(f.y); o[2]=f2bf(f.z); o[3]=f2bf(f.w);
  *(u16x4*)dst = o;
  if (g < 2048) biasuv[g] = (g < 1024) ? bu[g] : bv[g - 1024];
}

// ------------- T matrices: T[h] = (Wm U)(Wm V)^T, 64x64 per head ----------
__global__ void k_toep(const float* __restrict__ U1, const float* __restrict__ V1,
                       const float* __restrict__ U2, const float* __restrict__ V2,
                       u16* __restrict__ T1b, u16* __restrict__ T2b) {
  __shared__ float Us[512], Vs[512];
  int bid = blockIdx.x, t = threadIdx.x;
  int which = bid >> 6, rest = bid & 63, h = rest >> 3, seg = rest & 7;
  const float* U = which ? U2 : U1;
  const float* V = which ? V2 : V1;
  u16* T = which ? T2b : T1b;
  float scale = which ? 2.0f : 1.0f;
  for (int i = t; i < 512; i += 256) { Us[i] = U[h*512 + i]; Vs[i] = V[h*512 + i]; }
  __syncthreads();
  for (int q = 0; q < 2; ++q) {
    int e = seg * 512 + q * 256 + t;               // 0..4095 per head
    int i = e >> 6, j = e & 63;
    float pi = 1.0f / (float)(i + 1); float tvi = pi * 15.0f;
    int ii = min((int)floorf(tvi), 14); float fi = tvi - (float)ii;
    float pj = 1.0f / (float)(j + 1); float tvj = pj * 15.0f;
    int jj = min((int)floorf(tvj), 14); float fj = tvj - (float)jj;
    float s = 0.0f;
    #pragma unroll
    for (int r = 0; r < 32; ++r) {
      float a = (1.0f - fi) * Us[ii*32 + r] + fi * Us[(ii+1)*32 + r];
      float b = (1.0f - fj) * Vs[jj*32 + r] + fj * Vs[(jj+1)*32 + r];
      s += a * b;
    }
    T[h*4096 + i*64 + j] = f2bf(s * scale);
  }
}

// ================= 256x256 8-phase bf16 B^T GEMM (m201 template) ==========
// C[m,n] = sum_k A[m,k]*B[n,k] (+bias[n]); EPI 0: silu->bf16, EPI 1: f32.
// 512 thr = 8 waves (2M x 4N); BK=64; LDS = 2 buf x (A 256x64 + B 256x64) bf16
// = 128 KiB dynamic. Stage-op g: tile g/4, half g%4 (0:A lo,1:A hi,2:B lo,
// 3:B hi), buf (g/4)&1; each op = 2 x global_load_lds dwordx4 / thread.
// T2 swizzle: 16B slot s at row R holds global slot s^(R&7) (inverse-swz
// source, swizzled ds_read; LDS dest linear per rule #21).
template<int EPI>
__global__ __launch_bounds__(512, 2) void k_gemm256(
    const u16* __restrict__ A, const u16* __restrict__ B,
    const float* __restrict__ bias, void* __restrict__ C,
    int K, int nbn, int ldc) {
  extern __shared__ uint4 smem4[];
  u16* lds = (u16*)smem4;
  const int t = threadIdx.x;
  const int l = t & 63, w = t >> 6;
  const int wmi = w >> 2, wni = w & 3;          // 2 x 4 wave grid
  // T1: bijective XCD swizzle (gridDim.x % 8 == 0), bm-major tile order
  const int nwg = gridDim.x;
  const int lb = (blockIdx.x & 7) * (nwg >> 3) + (blockIdx.x >> 3);
  const int bm = lb / nbn, bn = lb % nbn;
  const u16* Ab = A + (size_t)bm * 256 * K;
  const u16* Bb = B + (size_t)bn * 256 * K;
  const int NT = K >> 6;
  const int NOPS = NT * 4;

  f32x4 acc[8][4];
  #pragma unroll
  for (int i = 0; i < 8; ++i)
    #pragma unroll
    for (int j = 0; j < 4; ++j) acc[i][j] = (f32x4){0.f, 0.f, 0.f, 0.f};

#define STAGE(gop) do {                                                      \
    int _g = (gop);                                                          \
    int _tile = _g >> 2, _half = _g & 3;                                     \
    int _kt = _tile << 6;                                                    \
    const u16* _src = (_half < 2) ? Ab : Bb;                                 \
    int _rowbase = (_half & 1) << 7;                                         \
    u16* _dst = lds + (_tile & 1) * 32768 + ((_half >= 2) ? 16384 : 0)       \
                + _rowbase * 64;                                             \
    _Pragma("unroll")                                                        \
    for (int _j = 0; _j < 2; ++_j) {                                         \
      int _idx = _j * 512 + t;                                               \
      int _rr = _idx >> 3, _s8 = _idx & 7;                                   \
      int _R = _rowbase + _rr;                                               \
      int _col = (_s8 ^ (_R & 7)) << 3;                                      \
      gload_lds16(_src + (size_t)_R * K + _kt + _col, _dst + _idx * 8);      \
    }                                                                        \
  } while (0)

  // prologue: ops 0..6 (tile0 fully + tile1 halves 0-2)
  #pragma unroll
  for (int g = 0; g < 7; ++g) STAGE(g);
  asm volatile("s_waitcnt vmcnt(6)");
  __builtin_amdgcn_s_barrier();

  for (int tile = 0; tile < NT; ++tile) {
    const int buf = tile & 1;
    const u16* As = lds + buf * 32768;
    const u16* Bs = As + 16384;
    #pragma unroll
    for (int p = 0; p < 4; ++p) {
      const int mq = (p >> 1) * 4, nq = (p & 1) * 2;
      // --- ds-read this phase's C-quadrant frags (12 x ds_read_b128)
      bf16x8 af[8], bfv[4];
      #pragma unroll
      for (int ks = 0; ks < 2; ++ks) {
        #pragma unroll
        for (int i = 0; i < 4; ++i) {
          int R = (wmi << 7) + (mq + i) * 16 + (l & 15);
          int q8 = ks * 4 + (l >> 4);
          af[ks*4+i] = *(const bf16x8*)&As[R * 64 + ((q8 ^ (R & 7)) << 3)];
        }
        #pragma unroll
        for (int i = 0; i < 2; ++i) {
          int R = (wni << 6) + (nq + i) * 16 + (l & 15);
          int q8 = ks * 4 + (l >> 4);
          bfv[ks*2+i] = *(const bf16x8*)&Bs[R * 64 + ((q8 ^ (R & 7)) << 3)];
        }
      }
      // --- issue one half-tile prefetch
      {
        int g = 7 + tile * 4 + p;
        if (g < NOPS) STAGE(g);
      }
      // --- counted vmcnt once per K-tile group (T4): never 0 in steady state
      if (p == 3) {
        if (tile < NT - 2)        asm volatile("s_waitcnt vmcnt(6)");
        else if (tile == NT - 2)  asm volatile("s_waitcnt vmcnt(0)");
      }
      __builtin_amdgcn_s_barrier();
      asm volatile("s_waitcnt lgkmcnt(0)");
      __builtin_amdgcn_s_setprio(1);
      #pragma unroll
      for (int ks = 0; ks < 2; ++ks)
        #pragma unroll
        for (int i = 0; i < 4; ++i)
          #pragma unroll
          for (int j = 0; j < 2; ++j)
            acc[mq+i][nq+j] = __builtin_amdgcn_mfma_f32_16x16x32_bf16(
                af[ks*4+i], bfv[ks*2+j], acc[mq+i][nq+j], 0, 0, 0);
      __builtin_amdgcn_s_setprio(0);
      __builtin_amdgcn_s_barrier();
    }
  }
#undef STAGE

  // ---------------- epilogue ----------------
  float bcol[4];
  #pragma unroll
  for (int nf = 0; nf < 4; ++nf)
    bcol[nf] = bias[bn * 256 + (wni << 6) + nf * 16 + (l & 15)];
  #pragma unroll
  for (int mf = 0; mf < 8; ++mf) {
    int gm0 = bm * 256 + (wmi << 7) + mf * 16 + (l >> 4) * 4;
    #pragma unroll
    for (int nf = 0; nf < 4; ++nf) {
      int gn = bn * 256 + (wni << 6) + nf * 16 + (l & 15);
      #pragma unroll
      for (int r = 0; r < 4; ++r) {
        float z = acc[mf][nf][r] + bcol[nf];
        size_t off = (size_t)(gm0 + r) * ldc + gn;
        if (EPI == 0) {
          z = z / (1.0f + __expf(-z));           // silu
          ((u16*)C)[off] = f2bf(z);
        } else {
          ((float*)C)[off] = z;
        }
      }
    }
  }
}

// ------------- mixing pass: per (b,outer,h): Out = T @ In (64x64 @ 64x128) -
template<int PASS>
__global__ __launch_bounds__(256) void k_mix(const u16* __restrict__ uv,
                                             u16* __restrict__ y,
                                             const u16* __restrict__ Tmat) {
  __shared__ alignas(16) u16 Ts[64 * 72];     // T padded rows (72 elems)
  __shared__ alignas(16) u32 VT[128 * 36];    // transposed input, swizzled
  int bid = blockIdx.x, t = threadIdx.x;
  int h = bid & 7, outer = (bid >> 3) & 63, b = bid >> 9;
  int l = t & 63, w = t >> 6;

  { // stage T[h] (64x64 bf16) into padded LDS
    const u16* Tg = Tmat + h * 4096;
    int rr = t >> 2, cc = (t & 3) * 16;
    const uint4* src = (const uint4*)(Tg + rr * 64 + cc);
    uint4 v0 = src[0], v1 = src[1];
    *(uint4*)&Ts[rr * 72 + cc] = v0;
    *(uint4*)&Ts[rr * 72 + cc + 8] = v1;
  }

  size_t inbase; size_t instride;
  if (PASS == 0) { inbase = ((size_t)(b*64 + outer) * 64) * 2048 + 1024 + h*128; instride = 2048; }
  else           { inbase = ((size_t)b * 4096 + outer) * 1024 + h*128;            instride = 65536; }
  const u16* inp = (PASS == 0) ? uv : (const u16*)y;

  #pragma unroll
  for (int a2 = 0; a2 < 2; ++a2) {
    int jp = (t >> 4) + a2 * 16;                 // row-pair 0..31 (rows 2jp,2jp+1)
    int dc = t & 15;                             // d-chunk of 8
    const u16* r0 = inp + inbase + (size_t)(2*jp) * instride + dc * 8;
    const u16* r1 = r0 + instride;
    uint4 av = *(const uint4*)r0;
    uint4 bv = *(const uint4*)r1;
    u32 a4[4] = {av.x, av.y, av.z, av.w};
    u32 b4[4] = {bv.x, bv.y, bv.z, bv.w};
    #pragma unroll
    for (int ww = 0; ww < 4; ++ww) {
      u32 lo = (a4[ww] & 0xffffu) | (b4[ww] << 16);        // d even
      u32 hi = (a4[ww] >> 16) | (b4[ww] & 0xffff0000u);    // d odd
      int d0 = dc * 8 + 2 * ww, d1 = d0 + 1;
      VT[d0 * 36 + (jp ^ ((((u32)d0 >> 3) & 7) << 2))] = lo;
      VT[d1 * 36 + (jp ^ ((((u32)d1 >> 3) & 7) << 2))] = hi;
    }
  }
  __syncthreads();

  f32x4 acc[8];
  #pragma unroll
  for (int nf = 0; nf < 8; ++nf) acc[nf] = (f32x4){0.f, 0.f, 0.f, 0.f};
  #pragma unroll
  for (int ks = 0; ks < 2; ++ks) {
    bf16x8 af = *(const bf16x8*)&Ts[(w*16 + (l & 15)) * 72 + ks*32 + (l >> 4)*8];
    #pragma unroll
    for (int nf = 0; nf < 8; ++nf) {
      int d  = nf * 16 + (l & 15);
      int kd = ks * 16 + (l >> 4) * 4;
      u32 dw = (u32)d * 36 + ((u32)kd ^ ((((u32)d >> 3) & 7) << 2));
      bf16x8 bfv = *(const bf16x8*)&VT[dw];
      acc[nf] = __builtin_amdgcn_mfma_f32_16x16x32_bf16(af, bfv, acc[nf], 0, 0, 0);
    }
  }

  size_t obase, ostride, ubase = 0;
  if (PASS == 0) { obase = ((size_t)(b*64 + outer) * 64) * 1024 + h*128; ostride = 1024; }
  else {
    obase = ((size_t)b * 4096 + outer) * 1024 + h*128; ostride = 65536;
    ubase = ((size_t)b * 4096 + outer) * 2048 + h*128;
  }
  #pragma unroll
  for (int nf = 0; nf < 8; ++nf) {
    int d = nf * 16 + (l & 15);
    #pragma unroll
    for (int r = 0; r < 4; ++r) {
      int m = w * 16 + (l >> 4) * 4 + r;
      float val = acc[nf][r];
      if (PASS == 1) val *= bf2f(uv[ubase + (size_t)m * 131072 + d]);
      y[obase + (size_t)m * ostride + d] = f2bf(val);
    }
  }
}

// ---------------------------------------------------------------------------
extern "C" void kernel_launch(void* const* d_in, const int* in_sizes, int n_in,
                              void* d_out, int out_size, void* d_ws, size_t ws_size,
                              hipStream_t stream) {
  const float* x  = (const float*)d_in[0];
  const float* Wu = (const float*)d_in[1];
  const float* bu = (const float*)d_in[2];
  const float* Wv = (const float*)d_in[3];
  const float* bv = (const float*)d_in[4];
  const float* Wo = (const float*)d_in[5];
  const float* bo = (const float*)d_in[6];
  const float* U1 = (const float*)d_in[7];
  const float* V1 = (const float*)d_in[8];
  const float* U2 = (const float*)d_in[9];
  const float* V2 = (const float*)d_in[10];
  float* out = (float*)d_out;

  char* p = (char*)d_ws;
  u16*  xb     = (u16*)(p + 0);              //  67,108,864 B
  u16*  wuvb   = (u16*)(p + 67108864);       //   2,097,152 B
  u16*  wob    = (u16*)(p + 69206016);       //   1,048,576 B
  u16*  T1b    = (u16*)(p + 70254592);       //      65,536 B
  u16*  T2b    = (u16*)(p + 70320128);       //      65,536 B
  float* biasuv= (float*)(p + 70385664);     //       8,192 B
  u16*  uv     = (u16*)(p + 70393856);       // 268,435,456 B  (u|v, ld 2048)
  u16*  y      = (u16*)(p + 338829312);      // 134,217,728 B  -> end 473,047,040
  if (ws_size < 473047040ULL) return;        // insufficient scratch: visible fail

  // allow 128 KiB dynamic LDS (ignore failures; ROCm typically allows directly)
  (void)hipFuncSetAttribute((const void*)&k_gemm256<0>,
      hipFuncAttributeMaxDynamicSharedMemorySize, 131072);
  (void)hipFuncSetAttribute((const void*)&k_gemm256<1>,
      hipFuncAttributeMaxDynamicSharedMemorySize, 131072);

  k_conv_x<<<16384, 256, 0, stream>>>(x, xb);
  k_conv_w<<<1536, 256, 0, stream>>>(Wu, Wv, Wo, bu, bv, wuvb, wob, biasuv);
  k_toep<<<128, 256, 0, stream>>>(U1, V1, U2, V2, T1b, T2b);
  // uv = [silu(x Wu^T + bu) | silu(x Wv^T + bv)]  (M=65536, N=2048, K=512)
  k_gemm256<0><<<2048, 512, 131072, stream>>>(xb, wuvb, biasuv, (void*)uv, 512, 8, 2048);
  // y = T1-mix along W of v
  k_mix<0><<<8192, 256, 0, stream>>>(uv, y, T1b);
  // y = u * (2*T2)-mix along H of y   (in-place, gated)
  k_mix<1><<<8192, 256, 0, stream>>>(uv, y, T2b);
  // out = y Wo^T + bo  (M=65536, N=512, K=1024)
  k_gemm256<1><<<512, 512, 131072, stream>>>(y, wob, bo, (void*)out, 1024, 2, 512);
}

// Round 3
// 516.813 us; speedup vs baseline: 1.1982x; 1.0581x over previous
//
#include <hip/hip_runtime.h>
#include <hip/hip_bf16.h>

typedef unsigned short u16;
typedef unsigned int   u32;
typedef float  f32x4  __attribute__((ext_vector_type(4)));
typedef __bf16 bf16x8 __attribute__((ext_vector_type(8)));
typedef u16    u16x8  __attribute__((ext_vector_type(8)));
typedef u16    u16x4  __attribute__((ext_vector_type(4)));

__device__ __forceinline__ u16 f2bf(float f) {
  u32 x = __builtin_bit_cast(u32, f);
  x += 0x7fffu + ((x >> 16) & 1u);          // RNE
  return (u16)(x >> 16);
}
__device__ __forceinline__ float bf2f(u16 u) {
  return __builtin_bit_cast(float, (u32)u << 16);
}
__device__ __forceinline__ void gload_lds16(const u16* g, u16* l) {
  __builtin_amdgcn_global_load_lds(
      (const __attribute__((address_space(1))) void*)g,
      (__attribute__((address_space(3))) void*)l, 16, 0, 0);
}

// ---------------- convert x -> bf16 (each thread: 8 elems) ----------------
__global__ void k_conv_x(const float* __restrict__ x, u16* __restrict__ xb) {
  int g = blockIdx.x * 256 + threadIdx.x;          // 4,194,304 threads exact
  const float4* src = (const float4*)(x + (size_t)g * 8);
  float4 f0 = src[0], f1 = src[1];
  u16x8 o;
  o[0]=f2bf(f0.x); o[1]=f2bf(f0.y); o[2]=f2bf(f0.z); o[3]=f2bf(f0.w);
  o[4]=f2bf(f1.x); o[5]=f2bf(f1.y); o[6]=f2bf(f1.z); o[7]=f2bf(f1.w);
  *(u16x8*)(xb + (size_t)g * 8) = o;
}

// ------------- convert weights -> bf16, build concat bias -----------------
__global__ void k_conv_w(const float* __restrict__ Wu, const float* __restrict__ Wv,
                         const float* __restrict__ Wo, const float* __restrict__ bu,
                         const float* __restrict__ bv, u16* __restrict__ wuvb,
                         u16* __restrict__ wob, float* __restrict__ biasuv) {
  int g = blockIdx.x * 256 + threadIdx.x;          // 393,216 threads exact
  int e = g * 4;
  const float* src; u16* dst;
  if (e < 524288)        { src = Wu + e;             dst = wuvb + e; }
  else if (e < 1048576)  { src = Wv + (e - 524288);  dst = wuvb + e; }
  else                   { src = Wo + (e - 1048576); dst = wob + (e - 1048576); }
  float4 f = *(const float4*)src;
  u16x4 o; o[0]=f2bf(f.x); o[1]=f2bf(f.y); o[2]=f2bf(f.z); o[3]=f2bf(f.w);
  *(u16x4*)dst = o;
  if (g < 2048) biasuv[g] = (g < 1024) ? bu[g] : bv[g - 1024];
}

// ------------- T matrices: T[h] = (Wm U)(Wm V)^T, 64x64 per head ----------
__global__ void k_toep(const float* __restrict__ U1, const float* __restrict__ V1,
                       const float* __restrict__ U2, const float* __restrict__ V2,
                       u16* __restrict__ T1b, u16* __restrict__ T2b) {
  __shared__ float Us[512], Vs[512];
  int bid = blockIdx.x, t = threadIdx.x;
  int which = bid >> 6, rest = bid & 63, h = rest >> 3, seg = rest & 7;
  const float* U = which ? U2 : U1;
  const float* V = which ? V2 : V1;
  u16* T = which ? T2b : T1b;
  float scale = which ? 2.0f : 1.0f;
  for (int i = t; i < 512; i += 256) { Us[i] = U[h*512 + i]; Vs[i] = V[h*512 + i]; }
  __syncthreads();
  for (int q = 0; q < 2; ++q) {
    int e = seg * 512 + q * 256 + t;               // 0..4095 per head
    int i = e >> 6, j = e & 63;
    float pi = 1.0f / (float)(i + 1); float tvi = pi * 15.0f;
    int ii = min((int)floorf(tvi), 14); float fi = tvi - (float)ii;
    float pj = 1.0f / (float)(j + 1); float tvj = pj * 15.0f;
    int jj = min((int)floorf(tvj), 14); float fj = tvj - (float)jj;
    float s = 0.0f;
    #pragma unroll
    for (int r = 0; r < 32; ++r) {
      float a = (1.0f - fi) * Us[ii*32 + r] + fi * Us[(ii+1)*32 + r];
      float b = (1.0f - fj) * Vs[jj*32 + r] + fj * Vs[(jj+1)*32 + r];
      s += a * b;
    }
    T[h*4096 + i*64 + j] = f2bf(s * scale);
  }
}

// ================= 256x256 bf16 B^T GEMM, phase-gated 8-phase ==============
// C[m,n] = sum_k A[m,k]*B[n,k] (+bias[n]); EPI 0: silu->bf16, EPI 1: f32.
// 512 thr = 8 waves (wmi=w>>2 in 0..1, wni=w&3 in 0..3); BK=64; dbuf 128KiB.
// Wave owns m-frags {h*128 + wmi*64 + f*16}, h=0,1, f=0..3 (two 64-row strips)
// so ALL waves finish A-half0 reads by end of phase1, A-half1 by phase3, and
// B by phase0. Staging ops q: 0=A rows0-127, 1=A rows128-255, 2=B lo, 3=B hi.
// Issue: (t+1).A1 @p0, (t+2).B0B1 @p1, (t+2).A0 @p2 -> never writes a live
// region; steady waits vmcnt(12) @p1end, vmcnt(8) @p3end (counted, not 0).
template<int EPI>
__global__ __launch_bounds__(512, 2) void k_gemm256(
    const u16* __restrict__ A, const u16* __restrict__ B,
    const float* __restrict__ bias, void* __restrict__ C,
    int K, int nbn, int ldc) {
  extern __shared__ uint4 smem4[];
  u16* lds = (u16*)smem4;
  const int t = threadIdx.x;
  const int l = t & 63, w = t >> 6;
  const int wmi = w >> 2, wni = w & 3;
  // bijective XCD swizzle (gridDim.x % 8 == 0), bm-major tile order
  const int nwg = gridDim.x;
  const int lb = (blockIdx.x & 7) * (nwg >> 3) + (blockIdx.x >> 3);
  const int bm = lb / nbn, bn = lb % nbn;
  const u16* Ab = A + (size_t)bm * 256 * K;
  const u16* Bb = B + (size_t)bn * 256 * K;
  const int NT = K >> 6;

  f32x4 acc[8][4];                     // [h*4+f][nf]
  #pragma unroll
  for (int i = 0; i < 8; ++i)
    #pragma unroll
    for (int j = 0; j < 4; ++j) acc[i][j] = (f32x4){0.f, 0.f, 0.f, 0.f};

#define STAGE(gop) do {                                                      \
    int _g = (gop);                                                          \
    int _tile = _g >> 2, _half = _g & 3;                                     \
    int _kt = _tile << 6;                                                    \
    const u16* _src = (_half < 2) ? Ab : Bb;                                 \
    int _rowbase = (_half & 1) << 7;                                         \
    u16* _dst = lds + (_tile & 1) * 32768 + ((_half >= 2) ? 16384 : 0)       \
                + _rowbase * 64;                                             \
    _Pragma("unroll")                                                        \
    for (int _j = 0; _j < 2; ++_j) {                                         \
      int _idx = _j * 512 + t;                                               \
      int _rr = _idx >> 3, _s8 = _idx & 7;                                   \
      int _R = _rowbase + _rr;                                               \
      int _col = (_s8 ^ (_R & 7)) << 3;                                      \
      gload_lds16(_src + (size_t)_R * K + _kt + _col, _dst + _idx * 8);      \
    }                                                                        \
  } while (0)

#define READ_A(hh, fp) do {                                                  \
    _Pragma("unroll")                                                        \
    for (int ks = 0; ks < 2; ++ks)                                           \
      _Pragma("unroll")                                                      \
      for (int i = 0; i < 2; ++i) {                                          \
        int R = ((hh) << 7) + (wmi << 6) + ((fp) * 2 + i) * 16 + (l & 15);   \
        int q8 = ks * 4 + (l >> 4);                                          \
        af[ks*2+i] = *(const bf16x8*)&As[R * 64 + ((q8 ^ (R & 7)) << 3)];    \
      }                                                                      \
  } while (0)

#define MFMA_PHASE(hh, fp) do {                                              \
    __builtin_amdgcn_s_setprio(1);                                           \
    _Pragma("unroll")                                                        \
    for (int ks = 0; ks < 2; ++ks)                                           \
      _Pragma("unroll")                                                      \
      for (int i = 0; i < 2; ++i)                                            \
        _Pragma("unroll")                                                    \
        for (int nf = 0; nf < 4; ++nf)                                       \
          acc[(hh)*4+(fp)*2+i][nf] = __builtin_amdgcn_mfma_f32_16x16x32_bf16(\
              af[ks*2+i], bfv[ks*4+nf], acc[(hh)*4+(fp)*2+i][nf], 0, 0, 0);  \
    __builtin_amdgcn_s_setprio(0);                                           \
  } while (0)

  // prologue: tile0 {A0,A1,B0,B1} then tile1 {B0,B1,A0}; drain tile0 only.
  STAGE(0); STAGE(1); STAGE(2); STAGE(3);
  STAGE(6); STAGE(7); STAGE(4);
  asm volatile("s_waitcnt vmcnt(6)");
  __builtin_amdgcn_s_barrier();

  for (int tile = 0; tile < NT; ++tile) {
    const u16* As = lds + (tile & 1) * 32768;
    const u16* Bs = As + 16384;
    bf16x8 bfv[8];                       // [ks*4+nf], held all 4 phases
    bf16x8 af[4];                        // [ks*2+i], per phase

    // ---------- phase 0: B(8 reads) + A h0 f0-1; issue (t+1).A1 ----------
    #pragma unroll
    for (int ks = 0; ks < 2; ++ks)
      #pragma unroll
      for (int nf = 0; nf < 4; ++nf) {
        int R = (wni << 6) + nf * 16 + (l & 15);
        int q8 = ks * 4 + (l >> 4);
        bfv[ks*4+nf] = *(const bf16x8*)&Bs[R * 64 + ((q8 ^ (R & 7)) << 3)];
      }
    READ_A(0, 0);
    if (tile + 1 < NT) STAGE(4 * (tile + 1) + 1);
    __builtin_amdgcn_s_barrier();
    asm volatile("s_waitcnt lgkmcnt(0)");
    MFMA_PHASE(0, 0);
    __builtin_amdgcn_s_barrier();

    // ---------- phase 1: A h0 f2-3; issue (t+2).B0,B1; vmcnt gate ----------
    READ_A(0, 1);
    if (tile + 2 < NT) { STAGE(4*(tile+2)+2); STAGE(4*(tile+2)+3); }
    __builtin_amdgcn_s_barrier();
    asm volatile("s_waitcnt lgkmcnt(0)");
    MFMA_PHASE(0, 1);
    if (tile < NT - 2)       asm volatile("s_waitcnt vmcnt(12)");
    else if (tile == NT - 2) asm volatile("s_waitcnt vmcnt(8)");
    else                     asm volatile("s_waitcnt vmcnt(0)");
    __builtin_amdgcn_s_barrier();

    // ---------- phase 2: A h1 f0-1; issue (t+2).A0 ----------
    READ_A(1, 0);
    if (tile + 2 < NT) STAGE(4 * (tile + 2) + 0);
    __builtin_amdgcn_s_barrier();
    asm volatile("s_waitcnt lgkmcnt(0)");
    MFMA_PHASE(1, 0);
    __builtin_amdgcn_s_barrier();

    // ---------- phase 3: A h1 f2-3; vmcnt gate for next tile ----------
    READ_A(1, 1);
    __builtin_amdgcn_s_barrier();
    asm volatile("s_waitcnt lgkmcnt(0)");
    MFMA_PHASE(1, 1);
    if (tile < NT - 2)       asm volatile("s_waitcnt vmcnt(8)");
    else if (tile == NT - 2) asm volatile("s_waitcnt vmcnt(2)");
    __builtin_amdgcn_s_barrier();
  }
#undef STAGE
#undef READ_A
#undef MFMA_PHASE

  // ---------------- epilogue ----------------
  float bcol[4];
  #pragma unroll
  for (int nf = 0; nf < 4; ++nf)
    bcol[nf] = bias[bn * 256 + (wni << 6) + nf * 16 + (l & 15)];
  #pragma unroll
  for (int hf = 0; hf < 8; ++hf) {
    int gm0 = bm * 256 + (hf >> 2) * 128 + wmi * 64 + (hf & 3) * 16 + (l >> 4) * 4;
    #pragma unroll
    for (int nf = 0; nf < 4; ++nf) {
      int gn = bn * 256 + (wni << 6) + nf * 16 + (l & 15);
      #pragma unroll
      for (int r = 0; r < 4; ++r) {
        float z = acc[hf][nf][r] + bcol[nf];
        size_t off = (size_t)(gm0 + r) * ldc + gn;
        if (EPI == 0) {
          z = z / (1.0f + __expf(-z));           // silu
          ((u16*)C)[off] = f2bf(z);
        } else {
          ((float*)C)[off] = z;
        }
      }
    }
  }
}

// ------------- mixing pass: per (b,outer,h): Out = T @ In (64x64 @ 64x128) -
template<int PASS>
__global__ __launch_bounds__(256) void k_mix(const u16* __restrict__ uv,
                                             u16* __restrict__ y,
                                             const u16* __restrict__ Tmat) {
  __shared__ alignas(16) u16 Ts[64 * 72];     // T padded rows (72 elems)
  __shared__ alignas(16) u32 VT[128 * 36];    // transposed input, swizzled
  int bid = blockIdx.x, t = threadIdx.x;
  int h = bid & 7, outer = (bid >> 3) & 63, b = bid >> 9;
  int l = t & 63, w = t >> 6;

  { // stage T[h] (64x64 bf16) into padded LDS
    const u16* Tg = Tmat + h * 4096;
    int rr = t >> 2, cc = (t & 3) * 16;
    const uint4* src = (const uint4*)(Tg + rr * 64 + cc);
    uint4 v0 = src[0], v1 = src[1];
    *(uint4*)&Ts[rr * 72 + cc] = v0;
    *(uint4*)&Ts[rr * 72 + cc + 8] = v1;
  }

  size_t inbase; size_t instride;
  if (PASS == 0) { inbase = ((size_t)(b*64 + outer) * 64) * 2048 + 1024 + h*128; instride = 2048; }
  else           { inbase = ((size_t)b * 4096 + outer) * 1024 + h*128;            instride = 65536; }
  const u16* inp = (PASS == 0) ? uv : (const u16*)y;

  #pragma unroll
  for (int a2 = 0; a2 < 2; ++a2) {
    int jp = (t >> 4) + a2 * 16;                 // row-pair 0..31 (rows 2jp,2jp+1)
    int dc = t & 15;                             // d-chunk of 8
    const u16* r0 = inp + inbase + (size_t)(2*jp) * instride + dc * 8;
    const u16* r1 = r0 + instride;
    uint4 av = *(const uint4*)r0;
    uint4 bv = *(const uint4*)r1;
    u32 a4[4] = {av.x, av.y, av.z, av.w};
    u32 b4[4] = {bv.x, bv.y, bv.z, bv.w};
    #pragma unroll
    for (int ww = 0; ww < 4; ++ww) {
      u32 lo = (a4[ww] & 0xffffu) | (b4[ww] << 16);        // d even
      u32 hi = (a4[ww] >> 16) | (b4[ww] & 0xffff0000u);    // d odd
      int d0 = dc * 8 + 2 * ww, d1 = d0 + 1;
      VT[d0 * 36 + (jp ^ ((((u32)d0 >> 3) & 7) << 2))] = lo;
      VT[d1 * 36 + (jp ^ ((((u32)d1 >> 3) & 7) << 2))] = hi;
    }
  }
  __syncthreads();

  f32x4 acc[8];
  #pragma unroll
  for (int nf = 0; nf < 8; ++nf) acc[nf] = (f32x4){0.f, 0.f, 0.f, 0.f};
  #pragma unroll
  for (int ks = 0; ks < 2; ++ks) {
    bf16x8 af = *(const bf16x8*)&Ts[(w*16 + (l & 15)) * 72 + ks*32 + (l >> 4)*8];
    #pragma unroll
    for (int nf = 0; nf < 8; ++nf) {
      int d  = nf * 16 + (l & 15);
      int kd = ks * 16 + (l >> 4) * 4;
      u32 dw = (u32)d * 36 + ((u32)kd ^ ((((u32)d >> 3) & 7) << 2));
      bf16x8 bfv = *(const bf16x8*)&VT[dw];
      acc[nf] = __builtin_amdgcn_mfma_f32_16x16x32_bf16(af, bfv, acc[nf], 0, 0, 0);
    }
  }

  size_t obase, ostride, ubase = 0;
  if (PASS == 0) { obase = ((size_t)(b*64 + outer) * 64) * 1024 + h*128; ostride = 1024; }
  else {
    obase = ((size_t)b * 4096 + outer) * 1024 + h*128; ostride = 65536;
    ubase = ((size_t)b * 4096 + outer) * 2048 + h*128;
  }
  #pragma unroll
  for (int nf = 0; nf < 8; ++nf) {
    int d = nf * 16 + (l & 15);
    #pragma unroll
    for (int r = 0; r < 4; ++r) {
      int m = w * 16 + (l >> 4) * 4 + r;
      float val = acc[nf][r];
      if (PASS == 1) val *= bf2f(uv[ubase + (size_t)m * 131072 + d]);
      y[obase + (size_t)m * ostride + d] = f2bf(val);
    }
  }
}

// ---------------------------------------------------------------------------
extern "C" void kernel_launch(void* const* d_in, const int* in_sizes, int n_in,
                              void* d_out, int out_size, void* d_ws, size_t ws_size,
                              hipStream_t stream) {
  const float* x  = (const float*)d_in[0];
  const float* Wu = (const float*)d_in[1];
  const float* bu = (const float*)d_in[2];
  const float* Wv = (const float*)d_in[3];
  const float* bv = (const float*)d_in[4];
  const float* Wo = (const float*)d_in[5];
  const float* bo = (const float*)d_in[6];
  const float* U1 = (const float*)d_in[7];
  const float* V1 = (const float*)d_in[8];
  const float* U2 = (const float*)d_in[9];
  const float* V2 = (const float*)d_in[10];
  float* out = (float*)d_out;

  char* p = (char*)d_ws;
  u16*  xb     = (u16*)(p + 0);              //  67,108,864 B
  u16*  wuvb   = (u16*)(p + 67108864);       //   2,097,152 B
  u16*  wob    = (u16*)(p + 69206016);       //   1,048,576 B
  u16*  T1b    = (u16*)(p + 70254592);       //      65,536 B
  u16*  T2b    = (u16*)(p + 70320128);       //      65,536 B
  float* biasuv= (float*)(p + 70385664);     //       8,192 B
  u16*  uv     = (u16*)(p + 70393856);       // 268,435,456 B  (u|v, ld 2048)
  u16*  y      = (u16*)(p + 338829312);      // 134,217,728 B  -> end 473,047,040
  if (ws_size < 473047040ULL) return;        // insufficient scratch: visible fail

  // allow 128 KiB dynamic LDS (ignore failures; ROCm typically allows directly)
  (void)hipFuncSetAttribute((const void*)&k_gemm256<0>,
      hipFuncAttributeMaxDynamicSharedMemorySize, 131072);
  (void)hipFuncSetAttribute((const void*)&k_gemm256<1>,
      hipFuncAttributeMaxDynamicSharedMemorySize, 131072);

  k_conv_x<<<16384, 256, 0, stream>>>(x, xb);
  k_conv_w<<<1536, 256, 0, stream>>>(Wu, Wv, Wo, bu, bv, wuvb, wob, biasuv);
  k_toep<<<128, 256, 0, stream>>>(U1, V1, U2, V2, T1b, T2b);
  // uv = [silu(x Wu^T + bu) | silu(x Wv^T + bv)]  (M=65536, N=2048, K=512)
  k_gemm256<0><<<2048, 512, 131072, stream>>>(xb, wuvb, biasuv, (void*)uv, 512, 8, 2048);
  // y = T1-mix along W of v
  k_mix<0><<<8192, 256, 0, stream>>>(uv, y, T1b);
  // y = u * (2*T2)-mix along H of y   (in-place, gated)
  k_mix<1><<<8192, 256, 0, stream>>>(uv, y, T2b);
  // out = y Wo^T + bo  (M=65536, N=512, K=1024)
  k_gemm256<1><<<512, 512, 131072, stream>>>(y, wob, bo, (void*)out, 1024, 2, 512);
}